// Round 6
// baseline (441.453 us; speedup 1.0000x reference)
//
#include <hip/hip_runtime.h>
#include <hip/hip_bf16.h>
#include <stdint.h>

// ---------------------------------------------------------------------------
// RoPE attention (B=2, SQ=4096, SK=16448, H=1, D=256) for MI355X (gfx950).
// r5 (resubmit; r5 never benched — GPU timeout): attn_k unchanged from r4
// (proven). Aux pipeline rebuilt: coalesced LDS-staged projections (no s_load
// latency chains), ballot-based fused mask-detect+compaction, split k/v
// projection kernels.
// ---------------------------------------------------------------------------

typedef __attribute__((ext_vector_type(8))) short short8;   // 8 x bf16 bits
typedef __attribute__((ext_vector_type(4))) float f4;       // MFMA C/D frag

__device__ __forceinline__ unsigned short f2bf(float x) {
  union { float f; uint32_t u; } v; v.f = x;
  return (unsigned short)((v.u + 0x7FFFu + ((v.u >> 16) & 1u)) >> 16);  // RNE
}

__device__ __forceinline__ uint32_t cvtpk(float a, float b) {
  uint32_t r;
  asm("v_cvt_pk_bf16_f32 %0, %1, %2" : "=v"(r) : "v"(a), "v"(b));
  return r;  // lo16 = bf16(a), hi16 = bf16(b)
}

__device__ __forceinline__ void gl_lds16(const void* g, void* l) {
  __builtin_amdgcn_global_load_lds(
      (const __attribute__((address_space(1))) void*)g,
      (__attribute__((address_space(3))) void*)l, 16, 0, 0);
}

// ---- rope cos/sin table: [64 t][64 f] float2 (axial; x and y share it) -----
__global__ void rope_tab_k(float2* __restrict__ tab) {
  int idx = blockIdx.x * 256 + threadIdx.x;      // 4096
  int t = idx >> 6, f = idx & 63;
  float freq = __expf(-(float)f * (9.210340371976184f / 64.0f)); // 10000^-(f/64)
  float ang = (float)t * freq;
  tab[idx] = make_float2(cosf(ang), sinf(ang));
}

__device__ __forceinline__ int mask_at(const void* mk, int f, int i) {
  if (f == 0) return ((const int*)mk)[i] != 0;
  if (f == 1) return ((const float*)mk)[i] != 0.0f;
  return ((const unsigned char*)mk)[i] != 0;
}

// ---- fused mask dtype detect + ballot compaction (1 block per batch) -------
__global__ __launch_bounds__(256) void scan2_k(const void* __restrict__ mk,
                                               int* __restrict__ comp,
                                               int* __restrict__ ncomp) {
  __shared__ int swc[4];
  __shared__ int sflag;
  const int b = blockIdx.x, t = threadIdx.x;
  const int w4 = t >> 6, lane = t & 63;
  // dtype detect on first 8KB (safe under all 3 interpretations)
  int okI = 1, okF = 1;
  const unsigned int* mw = (const unsigned int*)mk;
  for (int i = t; i < 2048; i += 256) {
    unsigned int x = mw[i];
    okI &= (x <= 1u);
    okF &= (x == 0u || x == 0x3F800000u);
  }
  okI = __all(okI); okF = __all(okF);
  if (t == 0) sflag = 3;
  __syncthreads();
  if (lane == 0) atomicAnd(&sflag, (okI ? 1 : 0) | (okF ? 2 : 0));
  __syncthreads();
  const int f = (sflag & 1) ? 0 : ((sflag & 2) ? 1 : 2);
  // ballot-based stable compaction
  const int base = b * 16448;
  int* cb = comp + base;
  int running = 0;
  for (int it = 0; it < 65; ++it) {
    const int i = it * 256 + t;
    const int pred = (i < 16448) ? mask_at(mk, f, base + i) : 0;
    const unsigned long long bal = __ballot(pred);
    if (lane == 0) swc[w4] = __popcll(bal);
    __syncthreads();
    int wpre = 0, tot = 0;
#pragma unroll
    for (int ww = 0; ww < 4; ++ww) {
      int v = swc[ww];
      tot += v;
      if (ww < w4) wpre += v;
    }
    if (pred)
      cb[running + wpre + __popcll(bal & ((1ull << lane) - 1ull))] = i;
    running += tot;
    __syncthreads();
  }
  if (t == 0) ncomp[b] = running;
}

// ---- Q projection + rope + 1/16 scale -> bf16 qh[8192][256] ----------------
// 16 rows/block staged in LDS (coalesced float4), compute via b128 broadcast.
__global__ __launch_bounds__(256) void qproj_k(
    const float* __restrict__ q, const float* __restrict__ wq,
    const float* __restrict__ bq, const float2* __restrict__ tab,
    unsigned short* __restrict__ qh) {
  __shared__ float qs[16][256];
  const int c = threadIdx.x;
  const int rb = blockIdx.x * 16;
#pragma unroll
  for (int i = 0; i < 4; ++i) {
    const int idx = i * 256 + c;                 // 0..1023
    const int row = idx >> 6, f4i = idx & 63;
    *(float4*)&qs[row][f4i * 4] =
        *(const float4*)(q + (size_t)(rb + row) * 256 + f4i * 4);
  }
  __syncthreads();
  float acc[16];
  const float bias = bq[c];
#pragma unroll
  for (int r = 0; r < 16; ++r) acc[r] = bias;
  for (int ch = 0; ch < 4; ++ch) {
    float wreg[64];
#pragma unroll
    for (int j = 0; j < 64; ++j) wreg[j] = wq[(ch * 64 + j) * 256 + c];
#pragma unroll
    for (int r = 0; r < 16; ++r) {
      float a = acc[r];
#pragma unroll
      for (int j = 0; j < 64; j += 4) {
        const float4 x = *(const float4*)&qs[r][ch * 64 + j];
        a += x.x * wreg[j] + x.y * wreg[j + 1] + x.z * wreg[j + 2] + x.w * wreg[j + 3];
      }
      acc[r] = a;
    }
  }
  const int p = c >> 1;
#pragma unroll
  for (int r = 0; r < 16; ++r) {
    const int pos = (rb + r) & 4095;
    const float2 cs = (p < 64) ? tab[(pos & 63) * 64 + p]
                               : tab[(pos >> 6) * 64 + (p - 64)];
    const float v = acc[r];
    const float o = __shfl_xor(v, 1);
    const float res = v * cs.x + ((c & 1) ? o * cs.y : -o * cs.y);
    qh[(size_t)(rb + r) * 256 + c] = f2bf(res * 0.0625f);   // fold softmax scale
  }
}

// ---- K projection on COMPACTED keys (rope + permuted+swizzled store) -------
__global__ __launch_bounds__(256) void kproj_k(
    const float* __restrict__ kin, const float* __restrict__ wk,
    const float* __restrict__ bk, const float2* __restrict__ tab,
    const int* __restrict__ nker, const int* __restrict__ comp,
    const int* __restrict__ ncomp, unsigned short* __restrict__ kh) {
  __shared__ float xs[64][64];
  __shared__ int rowidx[64];
  const int c = threadIdx.x;
  const int kb = blockIdx.x, b = blockIdx.y;
  const int nc = ncomp[b];
  const int pad = (nc + 31) & ~31;
  if (kb * 64 >= pad) return;
  const int* cmp = comp + b * 16448;
  if (c < 64) rowidx[c] = (kb * 64 + c < nc) ? cmp[kb * 64 + c] : -1;
  __syncthreads();
  const float* inb = kin + (size_t)b * 16448 * 64;
#pragma unroll
  for (int i = 0; i < 4; ++i) {
    const int idx = i * 256 + c;                 // 0..1023 = 64 rows x 16 f4
    const int row = idx >> 4, f4i = idx & 15;
    const int ri = rowidx[row];
    float4 v = make_float4(0.f, 0.f, 0.f, 0.f);
    if (ri >= 0) v = *(const float4*)(inb + (size_t)ri * 64 + f4i * 4);
    *(float4*)&xs[row][f4i * 4] = v;
  }
  __syncthreads();
  float wreg[64];
#pragma unroll
  for (int j = 0; j < 64; ++j) wreg[j] = wk[j * 256 + c];
  const float bias = bk[c];
  const int nrope = 16448 - nker[0];
  const int p = c >> 1;
  for (int r0 = 0; r0 < 64; r0 += 4) {
    float a0 = bias, a1 = bias, a2 = bias, a3 = bias;
#pragma unroll
    for (int j = 0; j < 64; j += 4) {
      const float4 x0 = *(const float4*)&xs[r0 + 0][j];
      const float4 x1 = *(const float4*)&xs[r0 + 1][j];
      const float4 x2 = *(const float4*)&xs[r0 + 2][j];
      const float4 x3 = *(const float4*)&xs[r0 + 3][j];
      a0 += x0.x * wreg[j] + x0.y * wreg[j + 1] + x0.z * wreg[j + 2] + x0.w * wreg[j + 3];
      a1 += x1.x * wreg[j] + x1.y * wreg[j + 1] + x1.z * wreg[j + 2] + x1.w * wreg[j + 3];
      a2 += x2.x * wreg[j] + x2.y * wreg[j + 1] + x2.z * wreg[j + 2] + x2.w * wreg[j + 3];
      a3 += x3.x * wreg[j] + x3.y * wreg[j + 1] + x3.z * wreg[j + 2] + x3.w * wreg[j + 3];
    }
    float av[4] = {a0, a1, a2, a3};
#pragma unroll
    for (int rr = 0; rr < 4; ++rr) {
      const int row = r0 + rr;
      const int ci = kb * 64 + row;
      const int oldrow = rowidx[row];
      float a = (oldrow >= 0) ? av[rr] : 0.f;
      if (oldrow >= 0 && oldrow < nrope) {       // rope (uniform branch)
        const int pos = oldrow & 4095;
        const float2 cs = (p < 64) ? tab[(pos & 63) * 64 + p]
                                   : tab[(pos >> 6) * 64 + (p - 64)];
        const float o = __shfl_xor(a, 1);
        a = a * cs.x + ((c & 1) ? o * cs.y : -o * cs.y);
      }
      const int kk = ci & 31;
      const int rr2 = ((kk >> 2) & 1) * 16 + (kk >> 3) * 4 + (kk & 3);
      const size_t rowg = (size_t)(ci & ~31) + rr2;
      *(unsigned short*)((char*)kh + ((size_t)b * 16448 + rowg) * 512 +
                         ((2 * c) ^ ((rr2 & 7) << 4))) = f2bf(a);
    }
  }
}

// ---- V projection on COMPACTED keys -> transposed tiles --------------------
__global__ __launch_bounds__(256) void vproj_k(
    const float* __restrict__ vin, const float* __restrict__ wv,
    const float* __restrict__ bv, const int* __restrict__ comp,
    const int* __restrict__ ncomp, unsigned short* __restrict__ vt) {
  __shared__ float xs[64][64];
  __shared__ int rowidx[64];
  __shared__ unsigned short vlds[64 * 258];
  const int c = threadIdx.x;
  const int kb = blockIdx.x, b = blockIdx.y;
  const int nc = ncomp[b];
  const int pad = (nc + 31) & ~31;
  if (kb * 64 >= pad) return;
  const int* cmp = comp + b * 16448;
  if (c < 64) rowidx[c] = (kb * 64 + c < nc) ? cmp[kb * 64 + c] : -1;
  __syncthreads();
  const float* inb = vin + (size_t)b * 16448 * 64;
#pragma unroll
  for (int i = 0; i < 4; ++i) {
    const int idx = i * 256 + c;
    const int row = idx >> 4, f4i = idx & 15;
    const int ri = rowidx[row];
    float4 v = make_float4(0.f, 0.f, 0.f, 0.f);
    if (ri >= 0) v = *(const float4*)(inb + (size_t)ri * 64 + f4i * 4);
    *(float4*)&xs[row][f4i * 4] = v;
  }
  __syncthreads();
  float wreg[64];
#pragma unroll
  for (int j = 0; j < 64; ++j) wreg[j] = wv[j * 256 + c];
  const float bias = bv[c];
  for (int r0 = 0; r0 < 64; r0 += 4) {
    float a0 = bias, a1 = bias, a2 = bias, a3 = bias;
#pragma unroll
    for (int j = 0; j < 64; j += 4) {
      const float4 x0 = *(const float4*)&xs[r0 + 0][j];
      const float4 x1 = *(const float4*)&xs[r0 + 1][j];
      const float4 x2 = *(const float4*)&xs[r0 + 2][j];
      const float4 x3 = *(const float4*)&xs[r0 + 3][j];
      a0 += x0.x * wreg[j] + x0.y * wreg[j + 1] + x0.z * wreg[j + 2] + x0.w * wreg[j + 3];
      a1 += x1.x * wreg[j] + x1.y * wreg[j + 1] + x1.z * wreg[j + 2] + x1.w * wreg[j + 3];
      a2 += x2.x * wreg[j] + x2.y * wreg[j + 1] + x2.z * wreg[j + 2] + x2.w * wreg[j + 3];
      a3 += x3.x * wreg[j] + x3.y * wreg[j + 1] + x3.z * wreg[j + 2] + x3.w * wreg[j + 3];
    }
    float av[4] = {a0, a1, a2, a3};
#pragma unroll
    for (int rr = 0; rr < 4; ++rr) {
      const int row = r0 + rr;
      vlds[row * 258 + c] = f2bf((rowidx[row] >= 0) ? av[rr] : 0.f);
    }
  }
  __syncthreads();
  char* tb = (char*)vt + ((size_t)b * 514 + (size_t)kb * 2) * 16384;
#pragma unroll
  for (int ti = 0; ti < 2; ++ti) {
    union { uint32_t w[16]; uint4 v4[4]; } u;
#pragma unroll
    for (int kk = 0; kk < 32; kk += 2) {
      uint32_t lo = vlds[(ti * 32 + kk) * 258 + c];
      uint32_t hi = vlds[(ti * 32 + kk + 1) * 258 + c];
      u.w[kk >> 1] = lo | (hi << 16);
    }
#pragma unroll
    for (int qd = 0; qd < 4; ++qd)
      *(uint4*)(tb + (size_t)ti * 16384 + c * 64 + qd * 16) = u.v4[qd];
  }
}

// ---- flash attention, KV-split partials (UNCHANGED from r4, proven) --------
// grid (nseg*2 segb, 32 qb), 256 thr = 4 waves x 32 q rows (2 groups of 16).
// LDS: single 16KB K tile (32 key x 512B, permuted+swizzled rows), two-barrier
// staging. V^T read directly from global (L1/L2) in 4-reg batches.
__global__ __launch_bounds__(256, 2) void attn_k(
    const unsigned short* __restrict__ qh, const unsigned short* __restrict__ kh,
    const unsigned short* __restrict__ vt, const int* __restrict__ ncomp,
    float* __restrict__ part, int nseg) {
  __shared__ __align__(16) char lds[16384];
  const int tid = threadIdx.x;
  const int w = tid >> 6, ln = tid & 63;
  const int lr = ln & 15, lg = ln >> 4;
  const int segb = blockIdx.x;                 // seg*2+b (XCD = segb%8)
  const int qb = blockIdx.y;
  const int seg = segb >> 1, b = segb & 1;
  const int nc = ncomp[b];
  const int ntiles = (nc + 31) >> 5;
  const int t0 = seg * ntiles / nseg;
  const int t1 = (seg + 1) * ntiles / nseg;

  short8 qf[2][8];
  {
    const unsigned short* qr = qh + (size_t)(b * 4096 + qb * 128 + w * 32 + lr) * 256;
#pragma unroll
    for (int g = 0; g < 2; ++g)
#pragma unroll
      for (int kc = 0; kc < 8; ++kc)
        qf[g][kc] = *(const short8*)(qr + g * 16 * 256 + kc * 32 + lg * 8);
  }
  const f4 fz = {0.f, 0.f, 0.f, 0.f};
  f4 acc[2][16];
#pragma unroll
  for (int g = 0; g < 2; ++g)
#pragma unroll
    for (int i = 0; i < 16; ++i) acc[g][i] = fz;
  float m_[2] = {-1e30f, -1e30f}, l_[2] = {0.f, 0.f};

  const int S = (lr & 7) << 4;
  const int s6 = S & 64, Lo = (lg * 16) ^ (S & 48);
  const int baseE = lr * 512 + Lo + s6;        // even kc
  const int baseO = lr * 512 + Lo + (64 - s6); // odd kc

  const char* srcK = (const char*)kh + (size_t)b * 16448 * 512 + (size_t)t0 * 16384;
  const char* gV = (const char*)vt + (size_t)b * 514 * 16384 + (size_t)t0 * 16384
                   + lr * 64 + lg * 16;
  const int stoff = tid * 16;

  for (int it = t0; it < t1; ++it) {
    __syncthreads();                           // all waves done reading prev K
#pragma unroll
    for (int r = 0; r < 4; ++r)
      gl_lds16(srcK + r * 4096 + stoff, lds + r * 4096 + stoff);
    srcK += 16384;
    __syncthreads();                           // drains vmcnt -> K tile ready
    f4 s[2][2] = {{fz, fz}, {fz, fz}};
#pragma unroll
    for (int kc = 0; kc < 8; ++kc) {
      const int off = ((kc & 1) ? baseO : baseE) + (kc >> 1) * 128;
      short8 k0 = *(const short8*)(lds + off);
      short8 k1 = *(const short8*)(lds + off + 8192);
      s[0][0] = __builtin_amdgcn_mfma_f32_16x16x32_bf16(k0, qf[0][kc], s[0][0], 0, 0, 0);
      s[1][0] = __builtin_amdgcn_mfma_f32_16x16x32_bf16(k0, qf[1][kc], s[1][0], 0, 0, 0);
      s[0][1] = __builtin_amdgcn_mfma_f32_16x16x32_bf16(k1, qf[0][kc], s[0][1], 0, 0, 0);
      s[1][1] = __builtin_amdgcn_mfma_f32_16x16x32_bf16(k1, qf[1][kc], s[1][1], 0, 0, 0);
    }
    if (it * 32 + 32 > nc) {
#pragma unroll
      for (int nt = 0; nt < 2; ++nt)
#pragma unroll
        for (int j = 0; j < 4; ++j)
          if (it * 32 + lg * 8 + nt * 4 + j >= nc) {
            s[0][nt][j] = -30000.f; s[1][nt][j] = -30000.f;
          }
    }
    float tm[2];
#pragma unroll
    for (int g = 0; g < 2; ++g) {
      float t = fmaxf(fmaxf(fmaxf(s[g][0][0], s[g][0][1]), fmaxf(s[g][0][2], s[g][0][3])),
                      fmaxf(fmaxf(s[g][1][0], s[g][1][1]), fmaxf(s[g][1][2], s[g][1][3])));
      t = fmaxf(t, __shfl_xor(t, 16));
      t = fmaxf(t, __shfl_xor(t, 32));
      tm[g] = t;
    }
    if (!__all(tm[0] <= m_[0] + 8.f && tm[1] <= m_[1] + 8.f)) {   // defer-max
#pragma unroll
      for (int g = 0; g < 2; ++g) {
        const float mn = fmaxf(m_[g], tm[g]);
        const float sc = __expf(m_[g] - mn);
        m_[g] = mn; l_[g] *= sc;
#pragma unroll
        for (int dt = 0; dt < 16; ++dt)
#pragma unroll
          for (int j = 0; j < 4; ++j) acc[g][dt][j] *= sc;
      }
    }
    short8 pf[2];
#pragma unroll
    for (int g = 0; g < 2; ++g) {
      union { uint32_t u[4]; short8 v; } pk;
      float ts = 0.f;
#pragma unroll
      for (int nt = 0; nt < 2; ++nt)
#pragma unroll
        for (int jj = 0; jj < 4; jj += 2) {
          float e0 = __expf(s[g][nt][jj] - m_[g]);
          float e1 = __expf(s[g][nt][jj + 1] - m_[g]);
          ts += e0 + e1;
          pk.u[nt * 2 + (jj >> 1)] = cvtpk(e0, e1);
        }
      ts += __shfl_xor(ts, 16);
      ts += __shfl_xor(ts, 32);
      l_[g] += ts;
      pf[g] = pk.v;
    }
#pragma unroll
    for (int bt = 0; bt < 4; ++bt) {
      short8 vf[4];
#pragma unroll
      for (int i = 0; i < 4; ++i) vf[i] = *(const short8*)(gV + (bt * 4 + i) * 1024);
#pragma unroll
      for (int dt = 0; dt < 4; ++dt) {
        acc[0][bt * 4 + dt] = __builtin_amdgcn_mfma_f32_16x16x32_bf16(vf[dt], pf[0], acc[0][bt * 4 + dt], 0, 0, 0);
        acc[1][bt * 4 + dt] = __builtin_amdgcn_mfma_f32_16x16x32_bf16(vf[dt], pf[1], acc[1][bt * 4 + dt], 0, 0, 0);
      }
    }
    gV += 16384;
  }
  const int qrow = qb * 128 + w * 32 + lr;
#pragma unroll
  for (int g = 0; g < 2; ++g) {
    float* pp = part + ((size_t)segb * 4096 + qrow + g * 16) * 260;
#pragma unroll
    for (int dt = 0; dt < 16; ++dt) *(f4*)(pp + dt * 16 + lg * 4) = acc[g][dt];
    if (lg == 0) { pp[256] = m_[g]; pp[257] = l_[g]; }
  }
}

// ---- fused split-K combine + output GEMM -----------------------------------
__global__ __launch_bounds__(256) void cogemm_k(
    const float* __restrict__ part, int nseg, const float* __restrict__ wo,
    const float* __restrict__ bo, float* __restrict__ out) {
  __shared__ float rows[8][256];
  const int c = threadIdx.x;
  const int rb = blockIdx.x * 8;
  for (int r = 0; r < 8; ++r) {
    const int row = rb + r, b = row >> 12, rl = row & 4095;
    float M = -1e30f;
    for (int s = 0; s < nseg; ++s)
      M = fmaxf(M, part[(size_t)((s * 2 + b) * 4096 + rl) * 260 + 256]);
    float L = 0.f, val = 0.f;
    for (int s = 0; s < nseg; ++s) {
      size_t ix = (size_t)((s * 2 + b) * 4096 + rl) * 260;
      float wf = __expf(part[ix + 256] - M);
      L += part[ix + 257] * wf;
      val += part[ix + c] * wf;
    }
    rows[r][c] = val / L;
  }
  __syncthreads();
  float acc[8];
  const float bias = bo[c];
#pragma unroll
  for (int r = 0; r < 8; ++r) acc[r] = bias;
  for (int ch = 0; ch < 4; ++ch) {
    float wreg[64];
#pragma unroll
    for (int j = 0; j < 64; ++j) wreg[j] = wo[(ch * 64 + j) * 256 + c];
#pragma unroll
    for (int r = 0; r < 8; ++r) {
      const float* ir = &rows[r][ch * 64];
      float a = acc[r];
#pragma unroll
      for (int j = 0; j < 64; ++j) a += ir[j] * wreg[j];
      acc[r] = a;
    }
  }
#pragma unroll
  for (int r = 0; r < 8; ++r) out[(size_t)(rb + r) * 256 + c] = acc[r];
}

// ---------------------------------------------------------------------------
extern "C" void kernel_launch(void* const* d_in, const int* in_sizes, int n_in,
                              void* d_out, int out_size, void* d_ws, size_t ws_size,
                              hipStream_t stream) {
  const float* q  = (const float*)d_in[0];
  const float* k  = (const float*)d_in[1];
  const float* v  = (const float*)d_in[2];
  const void*  mk = d_in[3];
  const float* wq = (const float*)d_in[4];
  const float* bq = (const float*)d_in[5];
  const float* wk = (const float*)d_in[6];
  const float* bk = (const float*)d_in[7];
  const float* wv = (const float*)d_in[8];
  const float* bv = (const float*)d_in[9];
  const float* wo = (const float*)d_in[10];
  const float* bo = (const float*)d_in[11];
  const int* nker = (const int*)d_in[12];
  (void)in_sizes; (void)n_in; (void)out_size;

  char* ws = (char*)d_ws;
  size_t off = 0;
  auto alloc = [&](size_t sz) { size_t o = off; off = (off + sz + 255) & ~(size_t)255; return o; };
  const size_t o_tab  = alloc((size_t)64 * 64 * 8);          // rope table 32KB
  const size_t o_qh   = alloc((size_t)8192 * 256 * 2);       // bf16 Q (pre-scaled)
  const size_t o_kh   = alloc((size_t)2 * 16448 * 512);      // bf16 K compact (swz)
  const size_t o_vt   = alloc((size_t)2 * 514 * 16384);      // bf16 V^T tiles
  const size_t o_cmp  = alloc((size_t)2 * 16448 * 4);        // compaction map
  const size_t o_ncmp = alloc(256);
  const size_t o_part = off;                                 // split-K partials
  auto partsz = [](int s) { return (size_t)s * 2 * 4096 * 260 * 4; };
  int nseg = 8;
  while (nseg > 1 && o_part + partsz(nseg) > ws_size) nseg >>= 1;

  float2* tab        = (float2*)(ws + o_tab);
  unsigned short* qh = (unsigned short*)(ws + o_qh);
  unsigned short* kh = (unsigned short*)(ws + o_kh);
  unsigned short* vt = (unsigned short*)(ws + o_vt);
  int* comp          = (int*)(ws + o_cmp);
  int* ncomp         = (int*)(ws + o_ncmp);
  float* part        = (float*)(ws + o_part);

  rope_tab_k<<<dim3(16), dim3(256), 0, stream>>>(tab);
  scan2_k<<<dim3(2), dim3(256), 0, stream>>>(mk, comp, ncomp);
  qproj_k<<<dim3(512), dim3(256), 0, stream>>>(q, wq, bq, tab, qh);
  kproj_k<<<dim3(257, 2), dim3(256), 0, stream>>>(k, wk, bk, tab, nker, comp, ncomp, kh);
  vproj_k<<<dim3(257, 2), dim3(256), 0, stream>>>(v, wv, bv, comp, ncomp, vt);
  attn_k<<<dim3(nseg * 2, 32), dim3(256), 0, stream>>>(qh, kh, vt, ncomp, part, nseg);
  cogemm_k<<<dim3(1024), dim3(256), 0, stream>>>(part, nseg, wo, bo, (float*)d_out);
}

// Round 7
// 415.313 us; speedup vs baseline: 1.0629x; 1.0629x over previous
//
#include <hip/hip_runtime.h>
#include <hip/hip_bf16.h>
#include <stdint.h>

// ---------------------------------------------------------------------------
// RoPE attention (B=2, SQ=4096, SK=16448, H=1, D=256) for MI355X (gfx950).
// r7: (1) scan rebuilt: all-loads-upfront + single barrier (was 65 serialized
// barrier iterations on 2 CUs); rope table folded into same launch.
// (2) attn_k: K double-buffer, ONE __syncthreads per tile (no inline asm,
// no spills). qproj/kproj/vproj/cogemm byte-identical to r6.
// ---------------------------------------------------------------------------

typedef __attribute__((ext_vector_type(8))) short short8;   // 8 x bf16 bits
typedef __attribute__((ext_vector_type(4))) float f4;       // MFMA C/D frag

__device__ __forceinline__ unsigned short f2bf(float x) {
  union { float f; uint32_t u; } v; v.f = x;
  return (unsigned short)((v.u + 0x7FFFu + ((v.u >> 16) & 1u)) >> 16);  // RNE
}

__device__ __forceinline__ uint32_t cvtpk(float a, float b) {
  uint32_t r;
  asm("v_cvt_pk_bf16_f32 %0, %1, %2" : "=v"(r) : "v"(a), "v"(b));
  return r;  // lo16 = bf16(a), hi16 = bf16(b)
}

__device__ __forceinline__ void gl_lds16(const void* g, void* l) {
  __builtin_amdgcn_global_load_lds(
      (const __attribute__((address_space(1))) void*)g,
      (__attribute__((address_space(3))) void*)l, 16, 0, 0);
}

// ---- fused: mask detect + ballot compaction (blocks 0,1) + rope table ------
// Rope table: [64 t][64 f] float2 (axial; x and y share it), blocks 2..17.
__global__ __launch_bounds__(256) void scanrope_k(const void* __restrict__ mk,
                                                  int* __restrict__ comp,
                                                  int* __restrict__ ncomp,
                                                  float2* __restrict__ tab) {
  const int blk = blockIdx.x, t = threadIdx.x;
  if (blk >= 2) {                                // rope table
    const int idx = (blk - 2) * 256 + t;         // 0..4095
    const int tt = idx >> 6, f = idx & 63;
    const float freq = __expf(-(float)f * (9.210340371976184f / 64.0f));
    const float ang = (float)tt * freq;
    tab[idx] = make_float2(cosf(ang), sinf(ang));
    return;
  }
  __shared__ int cnt[4][65];
  __shared__ int sflag;
  const int b = blk, w4 = t >> 6, lane = t & 63;
  // dtype detect on first 8KB (safe under all 3 interpretations)
  int okI = 1, okF = 1;
  const unsigned int* mw = (const unsigned int*)mk;
  for (int i = t; i < 2048; i += 256) {
    const unsigned int x = mw[i];
    okI &= (x <= 1u);
    okF &= (x == 0u || x == 0x3F800000u);
  }
  okI = __all(okI); okF = __all(okF);
  if (t == 0) sflag = 3;
  __syncthreads();
  if (lane == 0) atomicAnd(&sflag, (okI ? 1 : 0) | (okF ? 2 : 0));
  __syncthreads();
  const int f = (sflag & 1) ? 0 : ((sflag & 2) ? 1 : 2);
  // load ALL mask values up-front (coalesced, independent -> pipelined)
  const unsigned int* mwb = (const unsigned int*)mk + b * 16448;
  const unsigned char* mbb = (const unsigned char*)mk + b * 16448;
  uint32_t v[65];
#pragma unroll
  for (int it = 0; it < 65; ++it) {
    const int i = it * 256 + t;
    uint32_t x = 0;
    if (i < 16448) x = (f < 2) ? mwb[i] : (uint32_t)mbb[i];
    v[it] = x;
  }
  // per-wave popcounts
#pragma unroll
  for (int it = 0; it < 65; ++it) {
    const unsigned long long bal = __ballot(v[it] != 0);
    if (lane == 0) cnt[w4][it] = __popcll(bal);
  }
  __syncthreads();                               // the ONE cross-wave barrier
  // prefix + scatter (cnt reads are wave-broadcast)
  int running = 0;
  int* cb = comp + b * 16448;
#pragma unroll
  for (int it = 0; it < 65; ++it) {
    const unsigned long long bal = __ballot(v[it] != 0);
    int wpre = 0;
#pragma unroll
    for (int ww = 0; ww < 4; ++ww)
      if (ww < w4) wpre += cnt[ww][it];
    if (v[it] != 0)
      cb[running + wpre + __popcll(bal & ((1ull << lane) - 1ull))] = it * 256 + t;
    running += cnt[0][it] + cnt[1][it] + cnt[2][it] + cnt[3][it];
  }
  if (t == 0) ncomp[b] = running;
}

// ---- Q projection + rope + 1/16 scale -> bf16 qh[8192][256] ----------------
__global__ __launch_bounds__(256) void qproj_k(
    const float* __restrict__ q, const float* __restrict__ wq,
    const float* __restrict__ bq, const float2* __restrict__ tab,
    unsigned short* __restrict__ qh) {
  __shared__ float qs[16][256];
  const int c = threadIdx.x;
  const int rb = blockIdx.x * 16;
#pragma unroll
  for (int i = 0; i < 4; ++i) {
    const int idx = i * 256 + c;                 // 0..1023
    const int row = idx >> 6, f4i = idx & 63;
    *(float4*)&qs[row][f4i * 4] =
        *(const float4*)(q + (size_t)(rb + row) * 256 + f4i * 4);
  }
  __syncthreads();
  float acc[16];
  const float bias = bq[c];
#pragma unroll
  for (int r = 0; r < 16; ++r) acc[r] = bias;
  for (int ch = 0; ch < 4; ++ch) {
    float wreg[64];
#pragma unroll
    for (int j = 0; j < 64; ++j) wreg[j] = wq[(ch * 64 + j) * 256 + c];
#pragma unroll
    for (int r = 0; r < 16; ++r) {
      float a = acc[r];
#pragma unroll
      for (int j = 0; j < 64; j += 4) {
        const float4 x = *(const float4*)&qs[r][ch * 64 + j];
        a += x.x * wreg[j] + x.y * wreg[j + 1] + x.z * wreg[j + 2] + x.w * wreg[j + 3];
      }
      acc[r] = a;
    }
  }
  const int p = c >> 1;
#pragma unroll
  for (int r = 0; r < 16; ++r) {
    const int pos = (rb + r) & 4095;
    const float2 cs = (p < 64) ? tab[(pos & 63) * 64 + p]
                               : tab[(pos >> 6) * 64 + (p - 64)];
    const float v = acc[r];
    const float o = __shfl_xor(v, 1);
    const float res = v * cs.x + ((c & 1) ? o * cs.y : -o * cs.y);
    qh[(size_t)(rb + r) * 256 + c] = f2bf(res * 0.0625f);   // fold softmax scale
  }
}

// ---- K projection on COMPACTED keys (rope + permuted+swizzled store) -------
__global__ __launch_bounds__(256) void kproj_k(
    const float* __restrict__ kin, const float* __restrict__ wk,
    const float* __restrict__ bk, const float2* __restrict__ tab,
    const int* __restrict__ nker, const int* __restrict__ comp,
    const int* __restrict__ ncomp, unsigned short* __restrict__ kh) {
  __shared__ float xs[64][64];
  __shared__ int rowidx[64];
  const int c = threadIdx.x;
  const int kb = blockIdx.x, b = blockIdx.y;
  const int nc = ncomp[b];
  const int pad = (nc + 31) & ~31;
  if (kb * 64 >= pad) return;
  const int* cmp = comp + b * 16448;
  if (c < 64) rowidx[c] = (kb * 64 + c < nc) ? cmp[kb * 64 + c] : -1;
  __syncthreads();
  const float* inb = kin + (size_t)b * 16448 * 64;
#pragma unroll
  for (int i = 0; i < 4; ++i) {
    const int idx = i * 256 + c;                 // 0..1023 = 64 rows x 16 f4
    const int row = idx >> 4, f4i = idx & 15;
    const int ri = rowidx[row];
    float4 v = make_float4(0.f, 0.f, 0.f, 0.f);
    if (ri >= 0) v = *(const float4*)(inb + (size_t)ri * 64 + f4i * 4);
    *(float4*)&xs[row][f4i * 4] = v;
  }
  __syncthreads();
  float wreg[64];
#pragma unroll
  for (int j = 0; j < 64; ++j) wreg[j] = wk[j * 256 + c];
  const float bias = bk[c];
  const int nrope = 16448 - nker[0];
  const int p = c >> 1;
  for (int r0 = 0; r0 < 64; r0 += 4) {
    float a0 = bias, a1 = bias, a2 = bias, a3 = bias;
#pragma unroll
    for (int j = 0; j < 64; j += 4) {
      const float4 x0 = *(const float4*)&xs[r0 + 0][j];
      const float4 x1 = *(const float4*)&xs[r0 + 1][j];
      const float4 x2 = *(const float4*)&xs[r0 + 2][j];
      const float4 x3 = *(const float4*)&xs[r0 + 3][j];
      a0 += x0.x * wreg[j] + x0.y * wreg[j + 1] + x0.z * wreg[j + 2] + x0.w * wreg[j + 3];
      a1 += x1.x * wreg[j] + x1.y * wreg[j + 1] + x1.z * wreg[j + 2] + x1.w * wreg[j + 3];
      a2 += x2.x * wreg[j] + x2.y * wreg[j + 1] + x2.z * wreg[j + 2] + x2.w * wreg[j + 3];
      a3 += x3.x * wreg[j] + x3.y * wreg[j + 1] + x3.z * wreg[j + 2] + x3.w * wreg[j + 3];
    }
    float av[4] = {a0, a1, a2, a3};
#pragma unroll
    for (int rr = 0; rr < 4; ++rr) {
      const int row = r0 + rr;
      const int ci = kb * 64 + row;
      const int oldrow = rowidx[row];
      float a = (oldrow >= 0) ? av[rr] : 0.f;
      if (oldrow >= 0 && oldrow < nrope) {       // rope (uniform branch)
        const int pos = oldrow & 4095;
        const float2 cs = (p < 64) ? tab[(pos & 63) * 64 + p]
                                   : tab[(pos >> 6) * 64 + (p - 64)];
        const float o = __shfl_xor(a, 1);
        a = a * cs.x + ((c & 1) ? o * cs.y : -o * cs.y);
      }
      const int kk = ci & 31;
      const int rr2 = ((kk >> 2) & 1) * 16 + (kk >> 3) * 4 + (kk & 3);
      const size_t rowg = (size_t)(ci & ~31) + rr2;
      *(unsigned short*)((char*)kh + ((size_t)b * 16448 + rowg) * 512 +
                         ((2 * c) ^ ((rr2 & 7) << 4))) = f2bf(a);
    }
  }
}

// ---- V projection on COMPACTED keys -> transposed tiles --------------------
__global__ __launch_bounds__(256) void vproj_k(
    const float* __restrict__ vin, const float* __restrict__ wv,
    const float* __restrict__ bv, const int* __restrict__ comp,
    const int* __restrict__ ncomp, unsigned short* __restrict__ vt) {
  __shared__ float xs[64][64];
  __shared__ int rowidx[64];
  __shared__ unsigned short vlds[64 * 258];
  const int c = threadIdx.x;
  const int kb = blockIdx.x, b = blockIdx.y;
  const int nc = ncomp[b];
  const int pad = (nc + 31) & ~31;
  if (kb * 64 >= pad) return;
  const int* cmp = comp + b * 16448;
  if (c < 64) rowidx[c] = (kb * 64 + c < nc) ? cmp[kb * 64 + c] : -1;
  __syncthreads();
  const float* inb = vin + (size_t)b * 16448 * 64;
#pragma unroll
  for (int i = 0; i < 4; ++i) {
    const int idx = i * 256 + c;
    const int row = idx >> 4, f4i = idx & 15;
    const int ri = rowidx[row];
    float4 v = make_float4(0.f, 0.f, 0.f, 0.f);
    if (ri >= 0) v = *(const float4*)(inb + (size_t)ri * 64 + f4i * 4);
    *(float4*)&xs[row][f4i * 4] = v;
  }
  __syncthreads();
  float wreg[64];
#pragma unroll
  for (int j = 0; j < 64; ++j) wreg[j] = wv[j * 256 + c];
  const float bias = bv[c];
  for (int r0 = 0; r0 < 64; r0 += 4) {
    float a0 = bias, a1 = bias, a2 = bias, a3 = bias;
#pragma unroll
    for (int j = 0; j < 64; j += 4) {
      const float4 x0 = *(const float4*)&xs[r0 + 0][j];
      const float4 x1 = *(const float4*)&xs[r0 + 1][j];
      const float4 x2 = *(const float4*)&xs[r0 + 2][j];
      const float4 x3 = *(const float4*)&xs[r0 + 3][j];
      a0 += x0.x * wreg[j] + x0.y * wreg[j + 1] + x0.z * wreg[j + 2] + x0.w * wreg[j + 3];
      a1 += x1.x * wreg[j] + x1.y * wreg[j + 1] + x1.z * wreg[j + 2] + x1.w * wreg[j + 3];
      a2 += x2.x * wreg[j] + x2.y * wreg[j + 1] + x2.z * wreg[j + 2] + x2.w * wreg[j + 3];
      a3 += x3.x * wreg[j] + x3.y * wreg[j + 1] + x3.z * wreg[j + 2] + x3.w * wreg[j + 3];
    }
    float av[4] = {a0, a1, a2, a3};
#pragma unroll
    for (int rr = 0; rr < 4; ++rr) {
      const int row = r0 + rr;
      vlds[row * 258 + c] = f2bf((rowidx[row] >= 0) ? av[rr] : 0.f);
    }
  }
  __syncthreads();
  char* tb = (char*)vt + ((size_t)b * 514 + (size_t)kb * 2) * 16384;
#pragma unroll
  for (int ti = 0; ti < 2; ++ti) {
    union { uint32_t w[16]; uint4 v4[4]; } u;
#pragma unroll
    for (int kk = 0; kk < 32; kk += 2) {
      uint32_t lo = vlds[(ti * 32 + kk) * 258 + c];
      uint32_t hi = vlds[(ti * 32 + kk + 1) * 258 + c];
      u.w[kk >> 1] = lo | (hi << 16);
    }
#pragma unroll
    for (int qd = 0; qd < 4; ++qd)
      *(uint4*)(tb + (size_t)ti * 16384 + c * 64 + qd * 16) = u.v4[qd];
  }
}

// ---- flash attention, KV-split partials ------------------------------------
// grid (nseg*2 segb, 32 qb), 256 thr = 4 waves x 32 q rows (2 groups of 16).
// LDS: K DOUBLE-buffer 2 x 16KB (32 key x 512B, permuted+swizzled rows).
// ONE __syncthreads per tile: stage(t+1)->buf^1 at top, compute(t) from buf,
// barrier (compiler drains vmcnt) at bottom. V^T direct from global (vf[4]).
__global__ __launch_bounds__(256, 2) void attn_k(
    const unsigned short* __restrict__ qh, const unsigned short* __restrict__ kh,
    const unsigned short* __restrict__ vt, const int* __restrict__ ncomp,
    float* __restrict__ part, int nseg) {
  __shared__ __align__(16) char lds[32768];
  const int tid = threadIdx.x;
  const int w = tid >> 6, ln = tid & 63;
  const int lr = ln & 15, lg = ln >> 4;
  const int segb = blockIdx.x;                 // seg*2+b (XCD = segb%8)
  const int qb = blockIdx.y;
  const int seg = segb >> 1, b = segb & 1;
  const int nc = ncomp[b];
  const int ntiles = (nc + 31) >> 5;
  const int t0 = seg * ntiles / nseg;
  const int t1 = (seg + 1) * ntiles / nseg;

  short8 qf[2][8];
  {
    const unsigned short* qr = qh + (size_t)(b * 4096 + qb * 128 + w * 32 + lr) * 256;
#pragma unroll
    for (int g = 0; g < 2; ++g)
#pragma unroll
      for (int kc = 0; kc < 8; ++kc)
        qf[g][kc] = *(const short8*)(qr + g * 16 * 256 + kc * 32 + lg * 8);
  }
  const f4 fz = {0.f, 0.f, 0.f, 0.f};
  f4 acc[2][16];
#pragma unroll
  for (int g = 0; g < 2; ++g)
#pragma unroll
    for (int i = 0; i < 16; ++i) acc[g][i] = fz;
  float m_[2] = {-1e30f, -1e30f}, l_[2] = {0.f, 0.f};

  const int S = (lr & 7) << 4;
  const int s6 = S & 64, Lo = (lg * 16) ^ (S & 48);
  const int baseE = lr * 512 + Lo + s6;        // even kc
  const int baseO = lr * 512 + Lo + (64 - s6); // odd kc

  const char* khb = (const char*)kh + (size_t)b * 16448 * 512;
  const char* gV = (const char*)vt + (size_t)b * 514 * 16384 + (size_t)t0 * 16384
                   + lr * 64 + lg * 16;
  const char* srcK = khb + (size_t)(t0 + 1) * 16384;
  const int stoff = tid * 16;

  // prologue: stage tile t0 -> buf0; barrier drains it
  if (t0 < t1) {
#pragma unroll
    for (int r = 0; r < 4; ++r)
      gl_lds16(khb + (size_t)t0 * 16384 + r * 4096 + stoff, lds + r * 4096 + stoff);
  }
  __syncthreads();

  int cur = 0;
  for (int it = t0; it < t1; ++it) {
    // ---- stage next K tile into the other buffer (latency hides under compute)
    if (it + 1 < t1) {
      char* dst = lds + ((cur ^ 1) << 14);
#pragma unroll
      for (int r = 0; r < 4; ++r)
        gl_lds16(srcK + r * 4096 + stoff, dst + r * 4096 + stoff);
    }
    srcK += 16384;
    const char* kb_ = lds + (cur << 14);
    f4 s[2][2] = {{fz, fz}, {fz, fz}};
#pragma unroll
    for (int kc = 0; kc < 8; ++kc) {
      const int off = ((kc & 1) ? baseO : baseE) + (kc >> 1) * 128;
      short8 k0 = *(const short8*)(kb_ + off);
      short8 k1 = *(const short8*)(kb_ + off + 8192);
      s[0][0] = __builtin_amdgcn_mfma_f32_16x16x32_bf16(k0, qf[0][kc], s[0][0], 0, 0, 0);
      s[1][0] = __builtin_amdgcn_mfma_f32_16x16x32_bf16(k0, qf[1][kc], s[1][0], 0, 0, 0);
      s[0][1] = __builtin_amdgcn_mfma_f32_16x16x32_bf16(k1, qf[0][kc], s[0][1], 0, 0, 0);
      s[1][1] = __builtin_amdgcn_mfma_f32_16x16x32_bf16(k1, qf[1][kc], s[1][1], 0, 0, 0);
    }
    if (it * 32 + 32 > nc) {
#pragma unroll
      for (int nt = 0; nt < 2; ++nt)
#pragma unroll
        for (int j = 0; j < 4; ++j)
          if (it * 32 + lg * 8 + nt * 4 + j >= nc) {
            s[0][nt][j] = -30000.f; s[1][nt][j] = -30000.f;
          }
    }
    float tm[2];
#pragma unroll
    for (int g = 0; g < 2; ++g) {
      float t = fmaxf(fmaxf(fmaxf(s[g][0][0], s[g][0][1]), fmaxf(s[g][0][2], s[g][0][3])),
                      fmaxf(fmaxf(s[g][1][0], s[g][1][1]), fmaxf(s[g][1][2], s[g][1][3])));
      t = fmaxf(t, __shfl_xor(t, 16));
      t = fmaxf(t, __shfl_xor(t, 32));
      tm[g] = t;
    }
    if (!__all(tm[0] <= m_[0] + 8.f && tm[1] <= m_[1] + 8.f)) {   // defer-max
#pragma unroll
      for (int g = 0; g < 2; ++g) {
        const float mn = fmaxf(m_[g], tm[g]);
        const float sc = __expf(m_[g] - mn);
        m_[g] = mn; l_[g] *= sc;
#pragma unroll
        for (int dt = 0; dt < 16; ++dt)
#pragma unroll
          for (int j = 0; j < 4; ++j) acc[g][dt][j] *= sc;
      }
    }
    short8 pf[2];
#pragma unroll
    for (int g = 0; g < 2; ++g) {
      union { uint32_t u[4]; short8 v; } pk;
      float ts = 0.f;
#pragma unroll
      for (int nt = 0; nt < 2; ++nt)
#pragma unroll
        for (int jj = 0; jj < 4; jj += 2) {
          float e0 = __expf(s[g][nt][jj] - m_[g]);
          float e1 = __expf(s[g][nt][jj + 1] - m_[g]);
          ts += e0 + e1;
          pk.u[nt * 2 + (jj >> 1)] = cvtpk(e0, e1);
        }
      ts += __shfl_xor(ts, 16);
      ts += __shfl_xor(ts, 32);
      l_[g] += ts;
      pf[g] = pk.v;
    }
#pragma unroll
    for (int bt = 0; bt < 4; ++bt) {
      short8 vf[4];
#pragma unroll
      for (int i = 0; i < 4; ++i) vf[i] = *(const short8*)(gV + (bt * 4 + i) * 1024);
#pragma unroll
      for (int dt = 0; dt < 4; ++dt) {
        acc[0][bt * 4 + dt] = __builtin_amdgcn_mfma_f32_16x16x32_bf16(vf[dt], pf[0], acc[0][bt * 4 + dt], 0, 0, 0);
        acc[1][bt * 4 + dt] = __builtin_amdgcn_mfma_f32_16x16x32_bf16(vf[dt], pf[1], acc[1][bt * 4 + dt], 0, 0, 0);
      }
    }
    gV += 16384;
    __syncthreads();                           // drains staged loads; buffer handoff
    cur ^= 1;
  }
  const int qrow = qb * 128 + w * 32 + lr;
#pragma unroll
  for (int g = 0; g < 2; ++g) {
    float* pp = part + ((size_t)segb * 4096 + qrow + g * 16) * 260;
#pragma unroll
    for (int dt = 0; dt < 16; ++dt) *(f4*)(pp + dt * 16 + lg * 4) = acc[g][dt];
    if (lg == 0) { pp[256] = m_[g]; pp[257] = l_[g]; }
  }
}

// ---- fused split-K combine + output GEMM -----------------------------------
__global__ __launch_bounds__(256) void cogemm_k(
    const float* __restrict__ part, int nseg, const float* __restrict__ wo,
    const float* __restrict__ bo, float* __restrict__ out) {
  __shared__ float rows[8][256];
  const int c = threadIdx.x;
  const int rb = blockIdx.x * 8;
  for (int r = 0; r < 8; ++r) {
    const int row = rb + r, b = row >> 12, rl = row & 4095;
    float M = -1e30f;
    for (int s = 0; s < nseg; ++s)
      M = fmaxf(M, part[(size_t)((s * 2 + b) * 4096 + rl) * 260 + 256]);
    float L = 0.f, val = 0.f;
    for (int s = 0; s < nseg; ++s) {
      size_t ix = (size_t)((s * 2 + b) * 4096 + rl) * 260;
      float wf = __expf(part[ix + 256] - M);
      L += part[ix + 257] * wf;
      val += part[ix + c] * wf;
    }
    rows[r][c] = val / L;
  }
  __syncthreads();
  float acc[8];
  const float bias = bo[c];
#pragma unroll
  for (int r = 0; r < 8; ++r) acc[r] = bias;
  for (int ch = 0; ch < 4; ++ch) {
    float wreg[64];
#pragma unroll
    for (int j = 0; j < 64; ++j) wreg[j] = wo[(ch * 64 + j) * 256 + c];
#pragma unroll
    for (int r = 0; r < 8; ++r) {
      const float* ir = &rows[r][ch * 64];
      float a = acc[r];
#pragma unroll
      for (int j = 0; j < 64; ++j) a += ir[j] * wreg[j];
      acc[r] = a;
    }
  }
#pragma unroll
  for (int r = 0; r < 8; ++r) out[(size_t)(rb + r) * 256 + c] = acc[r];
}

// ---------------------------------------------------------------------------
extern "C" void kernel_launch(void* const* d_in, const int* in_sizes, int n_in,
                              void* d_out, int out_size, void* d_ws, size_t ws_size,
                              hipStream_t stream) {
  const float* q  = (const float*)d_in[0];
  const float* k  = (const float*)d_in[1];
  const float* v  = (const float*)d_in[2];
  const void*  mk = d_in[3];
  const float* wq = (const float*)d_in[4];
  const float* bq = (const float*)d_in[5];
  const float* wk = (const float*)d_in[6];
  const float* bk = (const float*)d_in[7];
  const float* wv = (const float*)d_in[8];
  const float* bv = (const float*)d_in[9];
  const float* wo = (const float*)d_in[10];
  const float* bo = (const float*)d_in[11];
  const int* nker = (const int*)d_in[12];
  (void)in_sizes; (void)n_in; (void)out_size;

  char* ws = (char*)d_ws;
  size_t off = 0;
  auto alloc = [&](size_t sz) { size_t o = off; off = (off + sz + 255) & ~(size_t)255; return o; };
  const size_t o_tab  = alloc((size_t)64 * 64 * 8);          // rope table 32KB
  const size_t o_qh   = alloc((size_t)8192 * 256 * 2);       // bf16 Q (pre-scaled)
  const size_t o_kh   = alloc((size_t)2 * 16448 * 512);      // bf16 K compact (swz)
  const size_t o_vt   = alloc((size_t)2 * 514 * 16384);      // bf16 V^T tiles
  const size_t o_cmp  = alloc((size_t)2 * 16448 * 4);        // compaction map
  const size_t o_ncmp = alloc(256);
  const size_t o_part = off;                                 // split-K partials
  auto partsz = [](int s) { return (size_t)s * 2 * 4096 * 260 * 4; };
  int nseg = 8;
  while (nseg > 1 && o_part + partsz(nseg) > ws_size) nseg >>= 1;

  float2* tab        = (float2*)(ws + o_tab);
  unsigned short* qh = (unsigned short*)(ws + o_qh);
  unsigned short* kh = (unsigned short*)(ws + o_kh);
  unsigned short* vt = (unsigned short*)(ws + o_vt);
  int* comp          = (int*)(ws + o_cmp);
  int* ncomp         = (int*)(ws + o_ncmp);
  float* part        = (float*)(ws + o_part);

  scanrope_k<<<dim3(18), dim3(256), 0, stream>>>(mk, comp, ncomp, tab);
  qproj_k<<<dim3(512), dim3(256), 0, stream>>>(q, wq, bq, tab, qh);
  kproj_k<<<dim3(257, 2), dim3(256), 0, stream>>>(k, wk, bk, tab, nker, comp, ncomp, kh);
  vproj_k<<<dim3(257, 2), dim3(256), 0, stream>>>(v, wv, bv, comp, ncomp, vt);
  attn_k<<<dim3(nseg * 2, 32), dim3(256), 0, stream>>>(qh, kh, vt, ncomp, part, nseg);
  cogemm_k<<<dim3(1024), dim3(256), 0, stream>>>(part, nseg, wo, bo, (float*)d_out);
}